// Round 11
// baseline (455.907 us; speedup 1.0000x reference)
//
#include <hip/hip_runtime.h>
#include <hip/hip_bf16.h>

#define F_ 2048
#define C_ 64
#define NE (C_ * F_)   // 131072 elements per [64,2048] activation
#define PGV 8          // gemv partials (f-chunk = 256, 2 MB contiguous/block)
#define PGM 16         // gemm partials (k-chunk = 128, two-stage + prefetch)

typedef __attribute__((ext_vector_type(4))) float f32x4;

// ---------------------------------------------------------------------------
// Kernel 1: P[fc][c][o] = sum_{f in chunk fc} p[f] * W[c,f,o]   (f32)
// grid (64 c, 8 f-chunks) = 512 blocks; each block streams a CONTIGUOUS
// 2 MB of W via nontemporal loads.
// ---------------------------------------------------------------------------
__global__ __launch_bounds__(256) void k_gemv(const float* __restrict__ p,
                                              const float* __restrict__ W,
                                              float* __restrict__ P0) {
    __shared__ float lp[256];
    const int c  = blockIdx.x;
    const int fc = blockIdx.y;
    const int t  = threadIdx.x;
    const int f0 = fc * 256;
    lp[t] = p[f0 + t];
    __syncthreads();

    const float* Wp = W + ((size_t)c << 22) + (size_t)f0 * F_;
    f32x4 aL = (f32x4)(0.f);
    f32x4 aH = (f32x4)(0.f);
#pragma unroll 8
    for (int ff = 0; ff < 256; ++ff) {
        float pv = lp[ff];
        f32x4 wl = __builtin_nontemporal_load((const f32x4*)(Wp + (size_t)ff * F_ + t * 4));
        f32x4 wh = __builtin_nontemporal_load((const f32x4*)(Wp + (size_t)ff * F_ + 1024 + t * 4));
        aL += pv * wl;
        aH += pv * wh;
    }
    float* dst = P0 + (size_t)fc * NE + c * F_;
    *(f32x4*)(dst + t * 4) = aL;
    *(f32x4*)(dst + 1024 + t * 4) = aH;
}

// ---------------------------------------------------------------------------
// Kernel 2: reduce 8 gemv partials + child_b -> relu -> GIN-1 agg -> H1 (f32)
// Block owns [64 c][8 o]; grid 256.
// ---------------------------------------------------------------------------
__global__ __launch_bounds__(256) void k_h1(const float* __restrict__ P0,
                                            const float* __restrict__ cb,
                                            float* __restrict__ H1) {
    __shared__ float xs[64 * 10];
    __shared__ float gs[32];
    __shared__ float aggL[8];
    const int t  = threadIdx.x;
    const int o0 = blockIdx.x * 8;
    const int c  = t >> 2;
    const int j  = (t & 3) * 2;

    float2 x = *(const float2*)(cb + c * F_ + o0 + j);
#pragma unroll
    for (int ps = 0; ps < PGV; ++ps) {
        float2 v = *(const float2*)(P0 + (size_t)ps * NE + c * F_ + o0 + j);
        x.x += v.x; x.y += v.y;
    }
    x.x = fmaxf(x.x, 0.f); x.y = fmaxf(x.y, 0.f);
    xs[c * 10 + j + 0] = x.x;
    xs[c * 10 + j + 1] = x.y;
    __syncthreads();

    if (t < 32) {
        const int o = t & 7, cg = t >> 3;
        float s = 0.f;
#pragma unroll
        for (int i = 0; i < 16; ++i) s += xs[(cg * 16 + i) * 10 + o];
        gs[cg * 8 + o] = s;
    }
    __syncthreads();
    if (t < 8) aggL[t] = gs[t] + gs[8 + t] + gs[16 + t] + gs[24 + t];
    __syncthreads();

    float2 r = x;
    if (c > 0) { r.x += aggL[j]; r.y += aggL[j + 1]; }
    *(float2*)(H1 + c * F_ + o0 + j) = r;
}

// ---------------------------------------------------------------------------
// Kernel 3: fused split-K GEMM. Partial phase identical to R10 (4x4 micro-
// tile, two-stage k=128, async prefetch). Then: threadfence + per-n-tile
// counter; the LAST arriving block (16th) reduces the 16 partials for its
// [64 m][64 n] tile and applies the epilogue inline:
//   MODE 0: T = relu(sum + bias)
//   MODE 1: H = BN(relu(sum + bias)) + GIN-2 agg (sum_c BN = 64*beta exactly)
//   MODE 2: out = BN(relu(sum + bias))
// Deterministic: reduce order is a fixed ps-loop regardless of winner.
// ---------------------------------------------------------------------------
template <int MODE>
__global__ __launch_bounds__(256) void k_gemm_f(const float* __restrict__ Hm,
                                                const float* __restrict__ W,
                                                const float* __restrict__ bias,
                                                const float* __restrict__ g,
                                                const float* __restrict__ be,
                                                float* __restrict__ P,
                                                int* __restrict__ cnt,
                                                float* __restrict__ Out) {
    __shared__ float sbuf[2 * 64 * 68 + 128];   // Ht | Ws, reused by epilogue
    float* Ht = sbuf;
    float* Ws = sbuf + 64 * 68;
    __shared__ int lastS;
    const int n0 = blockIdx.x * 64;
    const int k0 = blockIdx.y * 128;
    const int t  = threadIdx.x;
    const int tm4 = (t >> 4) * 4;
    const int tn4 = (t & 15) * 4;

    // --- stage half-0 ---
    float4 h0[4]; f32x4 w0[4];
#pragma unroll
    for (int it = 0; it < 4; ++it) {
        int s = t + it * 256;
        h0[it] = *(const float4*)&Hm[(s >> 4) * F_ + k0 + (s & 15) * 4];
        w0[it] = __builtin_nontemporal_load(
            (const f32x4*)&W[(size_t)(k0 + (s >> 4)) * F_ + n0 + (s & 15) * 4]);
    }
#pragma unroll
    for (int it = 0; it < 4; ++it) {
        int s = t + it * 256;
        int m = s >> 4, k4 = (s & 15) * 4;
        Ht[(k4 + 0) * 68 + m] = h0[it].x;
        Ht[(k4 + 1) * 68 + m] = h0[it].y;
        Ht[(k4 + 2) * 68 + m] = h0[it].z;
        Ht[(k4 + 3) * 68 + m] = h0[it].w;
        *(f32x4*)&Ws[(s >> 4) * 68 + (s & 15) * 4] = w0[it];
    }
    __syncthreads();

    // --- prefetch half-1 (in flight under half-0 compute) ---
    float4 h1[4]; f32x4 w1[4];
#pragma unroll
    for (int it = 0; it < 4; ++it) {
        int s = t + it * 256;
        h1[it] = *(const float4*)&Hm[(s >> 4) * F_ + k0 + 64 + (s & 15) * 4];
        w1[it] = __builtin_nontemporal_load(
            (const f32x4*)&W[(size_t)(k0 + 64 + (s >> 4)) * F_ + n0 + (s & 15) * 4]);
    }

    f32x4 acc0 = (f32x4)(0.f), acc1 = (f32x4)(0.f);
    f32x4 acc2 = (f32x4)(0.f), acc3 = (f32x4)(0.f);

#pragma unroll 4
    for (int k = 0; k < 64; ++k) {
        f32x4 a = *(const f32x4*)&Ht[k * 68 + tm4];
        f32x4 b = *(const f32x4*)&Ws[k * 68 + tn4];
        acc0 += a.x * b; acc1 += a.y * b; acc2 += a.z * b; acc3 += a.w * b;
    }
    __syncthreads();

#pragma unroll
    for (int it = 0; it < 4; ++it) {
        int s = t + it * 256;
        int m = s >> 4, k4 = (s & 15) * 4;
        Ht[(k4 + 0) * 68 + m] = h1[it].x;
        Ht[(k4 + 1) * 68 + m] = h1[it].y;
        Ht[(k4 + 2) * 68 + m] = h1[it].z;
        Ht[(k4 + 3) * 68 + m] = h1[it].w;
        *(f32x4*)&Ws[(s >> 4) * 68 + (s & 15) * 4] = w1[it];
    }
    __syncthreads();

#pragma unroll 4
    for (int k = 0; k < 64; ++k) {
        f32x4 a = *(const f32x4*)&Ht[k * 68 + tm4];
        f32x4 b = *(const f32x4*)&Ws[k * 68 + tn4];
        acc0 += a.x * b; acc1 += a.y * b; acc2 += a.z * b; acc3 += a.w * b;
    }

    float* dst = P + (size_t)blockIdx.y * NE + n0 + tn4;
    *(f32x4*)&dst[(tm4 + 0) * F_] = acc0;
    *(f32x4*)&dst[(tm4 + 1) * F_] = acc1;
    *(f32x4*)&dst[(tm4 + 2) * F_] = acc2;
    *(f32x4*)&dst[(tm4 + 3) * F_] = acc3;

    // --- semaphore: last block of this n-tile runs the epilogue ---
    __threadfence();
    __syncthreads();
    if (t == 0) lastS = (atomicAdd(&cnt[blockIdx.x], 1) == PGM - 1);
    __syncthreads();
    if (!lastS) return;
    __threadfence();

    // reduce 16 partials for [64 c][64 n] tile; thread t owns 4 (c, n4) items
    f32x4 v[4];
#pragma unroll
    for (int i = 0; i < 4; ++i) {
        int s  = t + i * 256;           // 0..1023
        int c  = s >> 4;
        int nl = (s & 15) * 4;
        f32x4 a = *(const f32x4*)&bias[n0 + nl];
#pragma unroll
        for (int ps = 0; ps < PGM; ++ps)
            a += *(const f32x4*)&P[(size_t)ps * NE + c * F_ + n0 + nl];
        a.x = fmaxf(a.x, 0.f); a.y = fmaxf(a.y, 0.f);
        a.z = fmaxf(a.z, 0.f); a.w = fmaxf(a.w, 0.f);
        v[i] = a;
        if (MODE == 0)
            *(f32x4*)&Out[c * F_ + n0 + nl] = a;
    }
    if (MODE == 0) return;

    // BatchNorm epilogue: stats per n over the 64 c values (block-local).
    float* xs = sbuf;                    // 64 x 68 (Ht region, free now)
    float* mL = sbuf + 64 * 68;          // 64
    float* rL = sbuf + 64 * 68 + 64;     // 64
#pragma unroll
    for (int i = 0; i < 4; ++i) {
        int s = t + i * 256;
        *(f32x4*)&xs[(s >> 4) * 68 + (s & 15) * 4] = v[i];
    }
    __syncthreads();
    if (t < 64) {
        float s = 0.f, s2 = 0.f;
#pragma unroll
        for (int c = 0; c < C_; ++c) {
            float x = xs[c * 68 + t];
            s += x; s2 += x * x;
        }
        float m   = s * (1.f / C_);
        float var = s2 * (1.f / C_) - m * m;
        mL[t] = m;
        rL[t] = 1.f / sqrtf(var + 1e-5f);
    }
    __syncthreads();

#pragma unroll
    for (int i = 0; i < 4; ++i) {
        int s  = t + i * 256;
        int c  = s >> 4;
        int nl = (s & 15) * 4;
        f32x4 g4 = *(const f32x4*)&g[n0 + nl];
        f32x4 b4 = *(const f32x4*)&be[n0 + nl];
        f32x4 r;
        r.x = (v[i].x - mL[nl + 0]) * rL[nl + 0] * g4.x + b4.x;
        r.y = (v[i].y - mL[nl + 1]) * rL[nl + 1] * g4.y + b4.y;
        r.z = (v[i].z - mL[nl + 2]) * rL[nl + 2] * g4.z + b4.z;
        r.w = (v[i].w - mL[nl + 3]) * rL[nl + 3] * g4.w + b4.w;
        if (MODE == 1 && c > 0)          // GIN-2 agg: sum_c BN = 64*beta
            r += (float)C_ * b4;
        *(f32x4*)&Out[c * F_ + n0 + nl] = r;
    }
}

extern "C" void kernel_launch(void* const* d_in, const int* in_sizes, int n_in,
                              void* d_out, int out_size, void* d_ws, size_t ws_size,
                              hipStream_t stream) {
    const float* p   = (const float*)d_in[0];
    const float* cW  = (const float*)d_in[1];
    const float* cb  = (const float*)d_in[2];
    const float* W1a = (const float*)d_in[3];
    const float* b1a = (const float*)d_in[4];
    const float* W1b = (const float*)d_in[5];
    const float* b1b = (const float*)d_in[6];
    const float* g1  = (const float*)d_in[7];
    const float* be1 = (const float*)d_in[8];
    const float* W2a = (const float*)d_in[9];
    const float* b2a = (const float*)d_in[10];
    const float* W2b = (const float*)d_in[11];
    const float* b2b = (const float*)d_in[12];
    const float* g2  = (const float*)d_in[13];
    const float* be2 = (const float*)d_in[14];
    float* out = (float*)d_out;
    float* ws  = (float*)d_ws;

    // P [16][64][2048] f32 (8.4 MB): gemv uses slots 0..7, GEMMs 0..15.
    float* P  = ws;
    float* H1 = ws + (size_t)16 * NE;
    float* T1 = H1 + NE;
    float* H2 = T1 + NE;
    float* T2 = H2 + NE;
    int*   cnt = (int*)(T2 + NE);       // 4 x 32 counters

    hipMemsetAsync(cnt, 0, 4 * 32 * sizeof(int), stream);

    // child MLP partials (the 1.07 GB streaming read)
    k_gemv<<<dim3(64, PGV), 256, 0, stream>>>(p, cW, P);
    // reduce + relu + GIN-1 aggregate
    k_h1<<<256, 256, 0, stream>>>(P, cb, H1);
    // GIN 1: GEMM+relu fused, then GEMM+BN+agg fused
    k_gemm_f<0><<<dim3(32, PGM), 256, 0, stream>>>(H1, W1a, b1a, nullptr, nullptr, P, cnt +  0, T1);
    k_gemm_f<1><<<dim3(32, PGM), 256, 0, stream>>>(T1, W1b, b1b, g1, be1,         P, cnt + 32, H2);
    // GIN 2: GEMM+relu fused, then GEMM+BN fused -> out
    k_gemm_f<0><<<dim3(32, PGM), 256, 0, stream>>>(H2, W2a, b2a, nullptr, nullptr, P, cnt + 64, T2);
    k_gemm_f<2><<<dim3(32, PGM), 256, 0, stream>>>(T2, W2b, b2b, g2, be2,         P, cnt + 96, out);
}

// Round 12
// 241.419 us; speedup vs baseline: 1.8884x; 1.8884x over previous
//
#include <hip/hip_runtime.h>
#include <hip/hip_bf16.h>

#define F_ 2048
#define C_ 64
#define NE (C_ * F_)   // 131072 elements per [64,2048] activation
#define PGV 4          // gemv partials (f-chunk = 512, 4 MB contiguous/block)
#define PGM 16         // gemm partials (k-chunk = 128, two-stage + prefetch)

typedef __attribute__((ext_vector_type(4))) float f32x4;

// ---------------------------------------------------------------------------
// Kernel 1: P[fc][c][o] = sum_{f in chunk fc} p[f] * W[c,f,o]   (f32)
// grid (64 c, 4 f-chunks) = 256 blocks (1/CU); each block streams a
// CONTIGUOUS 4 MB of W via nontemporal loads.
// ---------------------------------------------------------------------------
__global__ __launch_bounds__(256) void k_gemv(const float* __restrict__ p,
                                              const float* __restrict__ W,
                                              float* __restrict__ P0) {
    __shared__ float lp[512];
    const int c  = blockIdx.x;
    const int fc = blockIdx.y;
    const int t  = threadIdx.x;
    const int f0 = fc * 512;
    lp[t] = p[f0 + t];
    lp[t + 256] = p[f0 + t + 256];
    __syncthreads();

    const float* Wp = W + ((size_t)c << 22) + (size_t)f0 * F_;
    f32x4 aL = (f32x4)(0.f);
    f32x4 aH = (f32x4)(0.f);
#pragma unroll 8
    for (int ff = 0; ff < 512; ++ff) {
        float pv = lp[ff];
        f32x4 wl = __builtin_nontemporal_load((const f32x4*)(Wp + (size_t)ff * F_ + t * 4));
        f32x4 wh = __builtin_nontemporal_load((const f32x4*)(Wp + (size_t)ff * F_ + 1024 + t * 4));
        aL += pv * wl;
        aH += pv * wh;
    }
    float* dst = P0 + (size_t)fc * NE + c * F_;
    *(f32x4*)(dst + t * 4) = aL;
    *(f32x4*)(dst + 1024 + t * 4) = aH;
}

// ---------------------------------------------------------------------------
// Kernel 2: reduce 4 gemv partials + child_b -> relu -> GIN-1 agg -> H1 (f32)
// Block owns [64 c][8 o]; grid 256.
// ---------------------------------------------------------------------------
__global__ __launch_bounds__(256) void k_h1(const float* __restrict__ P0,
                                            const float* __restrict__ cb,
                                            float* __restrict__ H1) {
    __shared__ float xs[64 * 10];
    __shared__ float gs[32];
    __shared__ float aggL[8];
    const int t  = threadIdx.x;
    const int o0 = blockIdx.x * 8;
    const int c  = t >> 2;
    const int j  = (t & 3) * 2;

    float2 x = *(const float2*)(cb + c * F_ + o0 + j);
#pragma unroll
    for (int ps = 0; ps < PGV; ++ps) {
        float2 v = *(const float2*)(P0 + (size_t)ps * NE + c * F_ + o0 + j);
        x.x += v.x; x.y += v.y;
    }
    x.x = fmaxf(x.x, 0.f); x.y = fmaxf(x.y, 0.f);
    xs[c * 10 + j + 0] = x.x;
    xs[c * 10 + j + 1] = x.y;
    __syncthreads();

    if (t < 32) {                    // stage 1: 4 groups of 16 c
        const int o = t & 7, cg = t >> 3;
        float s = 0.f;
#pragma unroll
        for (int i = 0; i < 16; ++i) s += xs[(cg * 16 + i) * 10 + o];
        gs[cg * 8 + o] = s;
    }
    __syncthreads();
    if (t < 8) aggL[t] = gs[t] + gs[8 + t] + gs[16 + t] + gs[24 + t];
    __syncthreads();

    float2 r = x;
    if (c > 0) { r.x += aggL[j]; r.y += aggL[j + 1]; }
    *(float2*)(H1 + c * F_ + o0 + j) = r;
}

// ---------------------------------------------------------------------------
// Kernel 3: f32 GEMM partials, 4x4 micro-tile, two-stage k-chunk of 128.
// ALL 16 global loads (both halves) issued upfront, before any ds_write,
// so half-1's HBM latency hides under barrier + half-0 compute.
// grid (32 n-tiles of 64, 16 k-chunks) = 512 blocks (2/CU, 8 w/CU).
// ---------------------------------------------------------------------------
__global__ __launch_bounds__(256) void k_gemm(const float* __restrict__ Hm,
                                              const float* __restrict__ W,
                                              float* __restrict__ P) {
    __shared__ float Ht[64 * 68];   // [k][m]
    __shared__ float Ws[64 * 68];   // [k][n]
    const int n0 = blockIdx.x * 64;
    const int k0 = blockIdx.y * 128;
    const int t  = threadIdx.x;
    const int tm4 = (t >> 4) * 4;   // 16 m-groups of 4 rows
    const int tn4 = (t & 15) * 4;   // 16 n-groups of 4 cols

    // --- issue ALL loads: half-0 then half-1 (16 loads in flight) ---
    float4 h0[4]; f32x4 w0[4];
    float4 h1[4]; f32x4 w1[4];
#pragma unroll
    for (int it = 0; it < 4; ++it) {
        int s = t + it * 256;
        h0[it] = *(const float4*)&Hm[(s >> 4) * F_ + k0 + (s & 15) * 4];
        w0[it] = __builtin_nontemporal_load(
            (const f32x4*)&W[(size_t)(k0 + (s >> 4)) * F_ + n0 + (s & 15) * 4]);
    }
#pragma unroll
    for (int it = 0; it < 4; ++it) {
        int s = t + it * 256;
        h1[it] = *(const float4*)&Hm[(s >> 4) * F_ + k0 + 64 + (s & 15) * 4];
        w1[it] = __builtin_nontemporal_load(
            (const f32x4*)&W[(size_t)(k0 + 64 + (s >> 4)) * F_ + n0 + (s & 15) * 4]);
    }

    // --- stage half-0 to LDS (waits only on the first 8 loads) ---
#pragma unroll
    for (int it = 0; it < 4; ++it) {
        int s = t + it * 256;
        int m = s >> 4, k4 = (s & 15) * 4;
        Ht[(k4 + 0) * 68 + m] = h0[it].x;
        Ht[(k4 + 1) * 68 + m] = h0[it].y;
        Ht[(k4 + 2) * 68 + m] = h0[it].z;
        Ht[(k4 + 3) * 68 + m] = h0[it].w;
        *(f32x4*)&Ws[(s >> 4) * 68 + (s & 15) * 4] = w0[it];
    }
    __syncthreads();

    f32x4 acc0 = (f32x4)(0.f), acc1 = (f32x4)(0.f);
    f32x4 acc2 = (f32x4)(0.f), acc3 = (f32x4)(0.f);

#pragma unroll 4
    for (int k = 0; k < 64; ++k) {              // compute half-0
        f32x4 a = *(const f32x4*)&Ht[k * 68 + tm4];
        f32x4 b = *(const f32x4*)&Ws[k * 68 + tn4];
        acc0 += a.x * b; acc1 += a.y * b; acc2 += a.z * b; acc3 += a.w * b;
    }
    __syncthreads();                            // done reading half-0 LDS

#pragma unroll
    for (int it = 0; it < 4; ++it) {            // write half-1 to LDS
        int s = t + it * 256;
        int m = s >> 4, k4 = (s & 15) * 4;
        Ht[(k4 + 0) * 68 + m] = h1[it].x;
        Ht[(k4 + 1) * 68 + m] = h1[it].y;
        Ht[(k4 + 2) * 68 + m] = h1[it].z;
        Ht[(k4 + 3) * 68 + m] = h1[it].w;
        *(f32x4*)&Ws[(s >> 4) * 68 + (s & 15) * 4] = w1[it];
    }
    __syncthreads();

#pragma unroll 4
    for (int k = 0; k < 64; ++k) {              // compute half-1
        f32x4 a = *(const f32x4*)&Ht[k * 68 + tm4];
        f32x4 b = *(const f32x4*)&Ws[k * 68 + tn4];
        acc0 += a.x * b; acc1 += a.y * b; acc2 += a.z * b; acc3 += a.w * b;
    }

    float* dst = P + (size_t)blockIdx.y * NE + n0 + tn4;
    *(f32x4*)&dst[(tm4 + 0) * F_] = acc0;
    *(f32x4*)&dst[(tm4 + 1) * F_] = acc1;
    *(f32x4*)&dst[(tm4 + 2) * F_] = acc2;
    *(f32x4*)&dst[(tm4 + 3) * F_] = acc3;
}

// ---------------------------------------------------------------------------
// Kernel 4: T = relu(sum_p P[p] + bias[o])  (f32), float2, grid 256.
// ---------------------------------------------------------------------------
__global__ __launch_bounds__(256) void k_act(const float* __restrict__ P,
                                             const float* __restrict__ b,
                                             float* __restrict__ T) {
    const int e = (blockIdx.x * 256 + threadIdx.x) * 2;
    const int o = e & (F_ - 1);
    float2 a = *(const float2*)(b + o);
#pragma unroll 8
    for (int ps = 0; ps < PGM; ++ps) {
        float2 v = *(const float2*)(P + (size_t)ps * NE + e);
        a.x += v.x; a.y += v.y;
    }
    a.x = fmaxf(a.x, 0.f); a.y = fmaxf(a.y, 0.f);
    *(float2*)(T + e) = a;
}

// ---------------------------------------------------------------------------
// Kernel 5: reduce partials + bias -> relu -> BatchNorm -> (+ GIN-2 agg) -> H
// Block owns [64 c][8 o]; grid 256. sum_c(BN(x)) == 64*beta exactly.
// ---------------------------------------------------------------------------
__global__ __launch_bounds__(256) void k_bnh(const float* __restrict__ P,
                                             const float* __restrict__ bias,
                                             const float* __restrict__ g,
                                             const float* __restrict__ beta,
                                             float* __restrict__ H) {
    __shared__ float xs[64 * 10];
    __shared__ float gs[32];
    __shared__ float gs2[32];
    __shared__ float mL[8];
    __shared__ float rL[8];
    const int t  = threadIdx.x;
    const int o0 = blockIdx.x * 8;
    const int c  = t >> 2;
    const int j  = (t & 3) * 2;

    float2 x = *(const float2*)(bias + o0 + j);
#pragma unroll 8
    for (int ps = 0; ps < PGM; ++ps) {
        float2 v = *(const float2*)(P + (size_t)ps * NE + c * F_ + o0 + j);
        x.x += v.x; x.y += v.y;
    }
    x.x = fmaxf(x.x, 0.f); x.y = fmaxf(x.y, 0.f);
    xs[c * 10 + j + 0] = x.x;
    xs[c * 10 + j + 1] = x.y;
    __syncthreads();

    if (t < 32) {
        const int o = t & 7, cg = t >> 3;
        float s = 0.f, s2 = 0.f;
#pragma unroll
        for (int i = 0; i < 16; ++i) {
            float v = xs[(cg * 16 + i) * 10 + o];
            s += v; s2 += v * v;
        }
        gs[cg * 8 + o] = s;
        gs2[cg * 8 + o] = s2;
    }
    __syncthreads();
    if (t < 8) {
        float s  = gs[t] + gs[8 + t] + gs[16 + t] + gs[24 + t];
        float s2 = gs2[t] + gs2[8 + t] + gs2[16 + t] + gs2[24 + t];
        float m   = s * (1.f / C_);
        float var = s2 * (1.f / C_) - m * m;
        mL[t] = m;
        rL[t] = 1.f / sqrtf(var + 1e-5f);
    }
    __syncthreads();

    float2 g2v = *(const float2*)(g + o0 + j);
    float2 b2v = *(const float2*)(beta + o0 + j);
    float2 r;
    r.x = (x.x - mL[j + 0]) * rL[j + 0] * g2v.x + b2v.x;
    r.y = (x.y - mL[j + 1]) * rL[j + 1] * g2v.y + b2v.y;
    if (c > 0) {   // GIN-2 aggregate: sum_c xn = 64*beta exactly
        r.x += C_ * b2v.x;
        r.y += C_ * b2v.y;
    }
    *(float2*)(H + c * F_ + o0 + j) = r;
}

// ---------------------------------------------------------------------------
// Kernel 6: reduce partials + bias -> relu -> BatchNorm -> out (f32, no agg).
// Block owns [64 c][8 o]; grid 256.
// ---------------------------------------------------------------------------
__global__ __launch_bounds__(256) void k_bn_out(const float* __restrict__ P,
                                                const float* __restrict__ bias,
                                                const float* __restrict__ g,
                                                const float* __restrict__ beta,
                                                float* __restrict__ out) {
    __shared__ float xs[64 * 10];
    __shared__ float gs[32];
    __shared__ float gs2[32];
    __shared__ float mL[8];
    __shared__ float rL[8];
    const int t  = threadIdx.x;
    const int o0 = blockIdx.x * 8;
    const int c  = t >> 2;
    const int j  = (t & 3) * 2;

    float2 x = *(const float2*)(bias + o0 + j);
#pragma unroll 8
    for (int ps = 0; ps < PGM; ++ps) {
        float2 v = *(const float2*)(P + (size_t)ps * NE + c * F_ + o0 + j);
        x.x += v.x; x.y += v.y;
    }
    x.x = fmaxf(x.x, 0.f); x.y = fmaxf(x.y, 0.f);
    xs[c * 10 + j + 0] = x.x;
    xs[c * 10 + j + 1] = x.y;
    __syncthreads();

    if (t < 32) {
        const int o = t & 7, cg = t >> 3;
        float s = 0.f, s2 = 0.f;
#pragma unroll
        for (int i = 0; i < 16; ++i) {
            float v = xs[(cg * 16 + i) * 10 + o];
            s += v; s2 += v * v;
        }
        gs[cg * 8 + o] = s;
        gs2[cg * 8 + o] = s2;
    }
    __syncthreads();
    if (t < 8) {
        float s  = gs[t] + gs[8 + t] + gs[16 + t] + gs[24 + t];
        float s2 = gs2[t] + gs2[8 + t] + gs2[16 + t] + gs2[24 + t];
        float m   = s * (1.f / C_);
        float var = s2 * (1.f / C_) - m * m;
        mL[t] = m;
        rL[t] = 1.f / sqrtf(var + 1e-5f);
    }
    __syncthreads();

    float2 g2v = *(const float2*)(g + o0 + j);
    float2 b2v = *(const float2*)(beta + o0 + j);
    float2 r;
    r.x = (x.x - mL[j + 0]) * rL[j + 0] * g2v.x + b2v.x;
    r.y = (x.y - mL[j + 1]) * rL[j + 1] * g2v.y + b2v.y;
    *(float2*)(out + c * F_ + o0 + j) = r;
}

extern "C" void kernel_launch(void* const* d_in, const int* in_sizes, int n_in,
                              void* d_out, int out_size, void* d_ws, size_t ws_size,
                              hipStream_t stream) {
    const float* p   = (const float*)d_in[0];
    const float* cW  = (const float*)d_in[1];
    const float* cb  = (const float*)d_in[2];
    const float* W1a = (const float*)d_in[3];
    const float* b1a = (const float*)d_in[4];
    const float* W1b = (const float*)d_in[5];
    const float* b1b = (const float*)d_in[6];
    const float* g1  = (const float*)d_in[7];
    const float* be1 = (const float*)d_in[8];
    const float* W2a = (const float*)d_in[9];
    const float* b2a = (const float*)d_in[10];
    const float* W2b = (const float*)d_in[11];
    const float* b2b = (const float*)d_in[12];
    const float* g2  = (const float*)d_in[13];
    const float* be2 = (const float*)d_in[14];
    float* out = (float*)d_out;
    float* ws  = (float*)d_ws;

    // Partial buffer P [16][64][2048] f32 (8.4 MB): gemv uses slots 0..3,
    // each GEMM uses slots 0..15; reuse serialized by stream order.
    float* P  = ws;
    float* H1 = ws + (size_t)16 * NE;
    float* T1 = H1 + NE;
    float* H2 = T1 + NE;
    float* T2 = H2 + NE;

    // child MLP partials (the 1.07 GB streaming read, contiguous per block)
    k_gemv<<<dim3(64, PGV), 256, 0, stream>>>(p, cW, P);
    // reduce + relu + GIN-1 aggregate
    k_h1<<<256, 256, 0, stream>>>(P, cb, H1);
    // GIN 1
    k_gemm<<<dim3(32, PGM), 256, 0, stream>>>(H1, W1a, P);
    k_act<<<256, 256, 0, stream>>>(P, b1a, T1);
    k_gemm<<<dim3(32, PGM), 256, 0, stream>>>(T1, W1b, P);
    // relu + BN1 + GIN-2 aggregate
    k_bnh<<<256, 256, 0, stream>>>(P, b1b, g1, be1, H2);
    // GIN 2
    k_gemm<<<dim3(32, PGM), 256, 0, stream>>>(H2, W2a, P);
    k_act<<<256, 256, 0, stream>>>(P, b2a, T2);
    k_gemm<<<dim3(32, PGM), 256, 0, stream>>>(T2, W2b, P);
    // relu + BN2 -> output
    k_bn_out<<<256, 256, 0, stream>>>(P, b2b, g2, be2, out);
}